// Round 8
// baseline (110.978 us; speedup 1.0000x reference)
//
#include <hip/hip_runtime.h>
#include <hip/hip_bf16.h>
#include <math.h>

#define BS 8
#define NN 1024
#define FIN 256
#define HEADS 8
#define FO 64
#define NH (HEADS*FO)   /* 512 */
static constexpr float ALPHA = 0.2f;
static constexpr float LOG2E = 1.4426950408889634f;

typedef short bf16x8 __attribute__((ext_vector_type(8)));
typedef float f32x4  __attribute__((ext_vector_type(4)));
typedef unsigned short u16;
typedef unsigned u32;
typedef u16 u16x4v __attribute__((ext_vector_type(4)));
typedef u16 u16x8v __attribute__((ext_vector_type(8)));

__device__ __forceinline__ u16 f2b(float x) {
    __hip_bfloat16 b = __float2bfloat16(x);
    return *reinterpret_cast<u16*>(&b);
}
__device__ __forceinline__ float fexp2(float x) {
#if __has_builtin(__builtin_amdgcn_exp2f)
    return __builtin_amdgcn_exp2f(x);
#else
    float r; asm("v_exp_f32 %0, %1" : "=v"(r) : "v"(x)); return r;
#endif
}
__device__ __forceinline__ void gload_lds16(const void* g, void* l) {
    __builtin_amdgcn_global_load_lds(
        (const __attribute__((address_space(1))) unsigned int*)g,
        (__attribute__((address_space(3))) unsigned int*)l, 16, 0, 0);
}

// ---------------------------------------------------------------------------
// prep_misc: fused {pack_adj | cvt_h | cvt_wT+WaT} — all independent work,
// dispatched by blockIdx range. 8192 + 1024 + 32 = 9248 blocks.
// ---------------------------------------------------------------------------
__global__ __launch_bounds__(256) void prep_misc(const float* __restrict__ h,
                                                 const int* __restrict__ adj,
                                                 const float* __restrict__ W,
                                                 const float* __restrict__ avec,
                                                 u16* __restrict__ hb,
                                                 u16* __restrict__ WbT,
                                                 float* __restrict__ WaT,
                                                 u32* __restrict__ bits) {
    const int bid = blockIdx.x;
    const int t = threadIdx.x;
    if (bid < 8192) {
        // ---- pack_adj: 4 elems/lane (int4) + shuffle-assemble ----
        const int lane = t & 63;
        const size_t e0 = ((size_t)bid * 256 + t) * 4;
        const int4 v = *reinterpret_cast<const int4*>(adj + e0);
        u32 x = (v.x ? 1u : 0u) | (v.y ? 2u : 0u) | (v.z ? 4u : 0u) | (v.w ? 8u : 0u);
        {   const u32 r = (u32)__shfl_xor((int)x, 1);
            const int sh = (lane & 1) * 4;  x = (x << sh) | (r << (4 - sh)); }
        {   const u32 r = (u32)__shfl_xor((int)x, 2);
            const int sh = (lane & 2) * 4;  x = (x << sh) | (r << (8 - sh)); }
        {   const u32 r = (u32)__shfl_xor((int)x, 4);
            const int sh = (lane & 4) * 4;  x = (x << sh) | (r << (16 - sh)); }
        if ((lane & 7) == 0) bits[e0 >> 5] = x;
    } else if (bid < 9216) {
        // ---- cvt_h: h f32 -> bf16, 8 elems/thread ----
        const int i = ((bid - 8192) * 256 + t) * 8;
        const float4 v0 = *reinterpret_cast<const float4*>(h + i);
        const float4 v1 = *reinterpret_cast<const float4*>(h + i + 4);
        u16x8v o;
        o[0]=f2b(v0.x); o[1]=f2b(v0.y); o[2]=f2b(v0.z); o[3]=f2b(v0.w);
        o[4]=f2b(v1.x); o[5]=f2b(v1.y); o[6]=f2b(v1.z); o[7]=f2b(v1.w);
        *reinterpret_cast<u16x8v*>(hb + i) = o;
    } else {
        // ---- cvt_wT + WaT ----
        __shared__ float T[64][65];
        const int bb = bid - 9216;
        const int hh = bb & 7;
        const int n0 = hh * 64, k0 = (bb >> 3) * 64;
        const int r4 = t >> 6, c = t & 63;
        #pragma unroll
        for (int p = 0; p < 16; ++p) {
            const int r = p * 4 + r4;
            T[r][c] = W[(size_t)(k0 + r) * NH + n0 + c];
        }
        __syncthreads();
        #pragma unroll
        for (int p = 0; p < 16; ++p) {
            const int r = p * 4 + r4;
            WbT[(size_t)(n0 + r) * FIN + k0 + c] = f2b(T[c][r]);
        }
        if (t < 128) {
            const int kl = t & 63, sd = t >> 6;
            float s = 0.f;
            #pragma unroll
            for (int f = 0; f < 64; ++f)
                s += T[kl][f] * avec[hh * 128 + sd * 64 + f];
            WaT[(sd * 8 + hh) * FIN + k0 + kl] = s;
        }
    }
}

// ---------------------------------------------------------------------------
// calc_e (exact f32): wave per row i; e_src/e_dst = (h[i,:] @ WaT[c,:])*log2e
// ---------------------------------------------------------------------------
__global__ __launch_bounds__(256) void calc_e(const float* __restrict__ h,
                                              const float* __restrict__ WaT,
                                              float* __restrict__ esrc,
                                              float* __restrict__ edst) {
    const int t = threadIdx.x, wv = t >> 6, lane = t & 63;
    const int c = lane & 15, kg = lane >> 4;
    const int gi = blockIdx.x * 4 + wv;        // b*NN + i
    const float* hr = h   + (size_t)gi * FIN + kg * 64;
    const float* wr = WaT + (size_t)c  * FIN + kg * 64;
    float s = 0.f;
    #pragma unroll
    for (int q = 0; q < 16; ++q) {
        const float4 hv = *reinterpret_cast<const float4*>(hr + q * 4);
        const float4 wv4 = *reinterpret_cast<const float4*>(wr + q * 4);
        s += hv.x*wv4.x + hv.y*wv4.y + hv.z*wv4.z + hv.w*wv4.w;
    }
    s += __shfl_xor(s, 16);
    s += __shfl_xor(s, 32);
    if (lane < 16) {
        const int b = gi >> 10, i = gi & (NN - 1);
        s *= LOG2E;                            // exp2 domain
        if (c < 8) esrc[(size_t)(b * 8 + c) * NN + i] = s;
        else       edst[(size_t)(b * 8 + (c - 8)) * NN + i] = s;
    }
}

// ---------------------------------------------------------------------------
// gemm_whT: Wh = hb @ WbT^T, 64x64 tile, grid 1024, XCD-chunked. (unchanged)
// ---------------------------------------------------------------------------
__global__ __launch_bounds__(256) void gemm_whT(const u16* __restrict__ hb,
                                                const u16* __restrict__ WbT,
                                                u16* __restrict__ WhT) {
    __shared__ u16 Al[2][64 * 64];
    __shared__ u16 Bl[2][64 * 64];
    const int t = threadIdx.x, wv = t >> 6, lane = t & 63;
    const int g = lane >> 4, l15 = lane & 15;
    const int lid = (blockIdx.x & 7) * 128 + (blockIdx.x >> 3);
    const int m0 = (lid >> 3) * 64;
    const int h  = lid & 7;
    const int lr = lane >> 3;
    const int sch = (lane & 7) ^ lr;

    f32x4 acc[4] = {};

    auto stageA = [&](int buf, int k0) {
        #pragma unroll
        for (int c = 0; c < 2; ++c) {
            const int rowb = wv * 16 + c * 8;
            gload_lds16(hb + (size_t)(m0 + rowb + lr) * FIN + k0 + sch * 8,
                        &Al[buf][rowb * 64]);
        }
    };
    auto stageB = [&](int buf, int k0) {
        #pragma unroll
        for (int c = 0; c < 2; ++c) {
            const int rowb = wv * 16 + c * 8;
            gload_lds16(WbT + (size_t)(h * 64 + rowb + lr) * FIN + k0 + sch * 8,
                        &Bl[buf][rowb * 64]);
        }
    };

    stageA(0, 0); stageB(0, 0);
    __syncthreads();
    for (int kt = 0; kt < 4; ++kt) {
        const int buf = kt & 1;
        if (kt < 3) { stageA(buf ^ 1, (kt + 1) * 64); stageB(buf ^ 1, (kt + 1) * 64); }
        #pragma unroll
        for (int ks = 0; ks < 2; ++ks) {
            const int ch = (ks * 4 + g) ^ (l15 & 7);
            const bf16x8 afr = *reinterpret_cast<const bf16x8*>(
                &Al[buf][(wv * 16 + l15) * 64 + ch * 8]);
            #pragma unroll
            for (int n = 0; n < 4; ++n) {
                const bf16x8 bfr = *reinterpret_cast<const bf16x8*>(
                    &Bl[buf][(n * 16 + l15) * 64 + ch * 8]);
                acc[n] = __builtin_amdgcn_mfma_f32_16x16x32_bf16(afr, bfr, acc[n], 0, 0, 0);
            }
        }
        __syncthreads();
    }

    u16* scr = &Al[0][0];
    #pragma unroll
    for (int n = 0; n < 4; ++n) {
        u16x4v pk;
        #pragma unroll
        for (int r = 0; r < 4; ++r) pk[r] = f2b(acc[n][r]);
        *reinterpret_cast<u16x4v*>(&scr[(n * 16 + l15) * 72 + wv * 16 + g * 4]) = pk;
    }
    __syncthreads();
    const int bh  = (m0 >> 10) * HEADS + h;
    const int il0 = m0 & (NN - 1);
    const int f = t >> 2, q = t & 3;
    const u16x8v v0 = *reinterpret_cast<const u16x8v*>(&scr[f * 72 + q * 16]);
    const u16x8v v1 = *reinterpret_cast<const u16x8v*>(&scr[f * 72 + q * 16 + 8]);
    u16* dst = &WhT[((size_t)bh * 64 + f) * NN + il0 + q * 16];
    *reinterpret_cast<u16x8v*>(dst)     = v0;
    *reinterpret_cast<u16x8v*>(dst + 8) = v1;
}

// ---------------------------------------------------------------------------
// attn_pv v3: BARRIER-FREE. No LDS at all. V-fragments (16B contiguous in
// WhT), ed (broadcast) and bits (int4 / 4 steps) loaded straight from
// global (L1/L2-resident), 1-deep register pipeline. 4 independent waves
// per block, 16 rows each. Denominator via mfma(P, ones).
// ---------------------------------------------------------------------------
__global__ __launch_bounds__(256, 4) void attn_pv(const u32* __restrict__ bits,
                                                  const u16* __restrict__ WhT,
                                                  const float* __restrict__ esrc,
                                                  const float* __restrict__ edst,
                                                  float* __restrict__ out) {
    const int t = threadIdx.x, wv = t >> 6, lane = t & 63;
    const int g = lane >> 4, l15 = lane & 15;

    const int lid = (blockIdx.x & 7) * 128 + (blockIdx.x >> 3);
    const int it = lid & 15, h = (lid >> 4) & 7, b = lid >> 7;
    const int i0 = it * 64;
    const int bh = b * HEADS + h;
    const int rowi = i0 + wv * 16 + l15;

    const float es = esrc[(size_t)bh * NN + rowi];
    const u16*  whb = WhT + (size_t)bh * 64 * NN;
    const float* ed = edst + (size_t)bh * NN + 8 * g;
    const u32*  bitrow = bits + (size_t)(b * NN + rowi) * 32;

    const u16* vp0 = whb + (size_t)(0 * 16 + l15) * NN + 8 * g;
    const u16* vp1 = whb + (size_t)(1 * 16 + l15) * NN + 8 * g;
    const u16* vp2 = whb + (size_t)(2 * 16 + l15) * NN + 8 * g;
    const u16* vp3 = whb + (size_t)(3 * 16 + l15) * NN + 8 * g;

    f32x4 acc[4] = {};
    f32x4 dsum = {};
    bf16x8 ones;
    #pragma unroll
    for (int q = 0; q < 8; ++q) ones[q] = (short)0x3F80;   // bf16(1.0)

    // ---- 1-deep software pipeline (ed first so its wait doesn't drain V) ----
    float4 ne0 = *(const float4*)(ed);
    float4 ne1 = *(const float4*)(ed + 4);
    bf16x8 nv0 = *(const bf16x8*)(vp0);
    bf16x8 nv1 = *(const bf16x8*)(vp1);
    bf16x8 nv2 = *(const bf16x8*)(vp2);
    bf16x8 nv3 = *(const bf16x8*)(vp3);
    int4 bwcur  = *(const int4*)(bitrow);
    int4 bwnext = *(const int4*)(bitrow + 4);

    #pragma unroll 4
    for (int ks = 0; ks < 32; ++ks) {
        const bf16x8 v0 = nv0, v1 = nv1, v2 = nv2, v3 = nv3;
        const float4 e0 = ne0, e1 = ne1;
        const int km = ks & 3;   // compile-time under unroll 4
        const u32 word = (km == 0) ? (u32)bwcur.x : (km == 1) ? (u32)bwcur.y
                       : (km == 2) ? (u32)bwcur.z : (u32)bwcur.w;
        if (ks < 31) {           // prefetch ks+1
            const int o = (ks + 1) * 32;
            ne0 = *(const float4*)(ed + o);
            ne1 = *(const float4*)(ed + o + 4);
            nv0 = *(const bf16x8*)(vp0 + o);
            nv1 = *(const bf16x8*)(vp1 + o);
            nv2 = *(const bf16x8*)(vp2 + o);
            nv3 = *(const bf16x8*)(vp3 + o);
        }
        if (km == 3) {
            bwcur = bwnext;
            if (ks < 27) bwnext = *(const int4*)(bitrow + ks + 5);
        }

        const u32 byte_ = (word >> (8 * g)) & 0xffu;
        float ps[8];
        {
            float sv;
            sv = es + e0.x; sv = fmaxf(sv, ALPHA * sv); sv = (byte_ & 1u)        ? sv : -1e30f; ps[0] = fexp2(sv);
            sv = es + e0.y; sv = fmaxf(sv, ALPHA * sv); sv = ((byte_ >> 1) & 1u) ? sv : -1e30f; ps[1] = fexp2(sv);
            sv = es + e0.z; sv = fmaxf(sv, ALPHA * sv); sv = ((byte_ >> 2) & 1u) ? sv : -1e30f; ps[2] = fexp2(sv);
            sv = es + e0.w; sv = fmaxf(sv, ALPHA * sv); sv = ((byte_ >> 3) & 1u) ? sv : -1e30f; ps[3] = fexp2(sv);
            sv = es + e1.x; sv = fmaxf(sv, ALPHA * sv); sv = ((byte_ >> 4) & 1u) ? sv : -1e30f; ps[4] = fexp2(sv);
            sv = es + e1.y; sv = fmaxf(sv, ALPHA * sv); sv = ((byte_ >> 5) & 1u) ? sv : -1e30f; ps[5] = fexp2(sv);
            sv = es + e1.z; sv = fmaxf(sv, ALPHA * sv); sv = ((byte_ >> 6) & 1u) ? sv : -1e30f; ps[6] = fexp2(sv);
            sv = es + e1.w; sv = fmaxf(sv, ALPHA * sv); sv = ((byte_ >> 7) & 1u) ? sv : -1e30f; ps[7] = fexp2(sv);
        }
        union { u32 u[4]; bf16x8 v; } af;
        #pragma unroll
        for (int qp = 0; qp < 4; ++qp) {
            union { __hip_bfloat162 b2; u32 w; } cv;
            cv.b2 = __float22bfloat162_rn(make_float2(ps[2*qp], ps[2*qp+1]));
            af.u[qp] = cv.w;
        }
        acc[0] = __builtin_amdgcn_mfma_f32_16x16x32_bf16(af.v, v0, acc[0], 0, 0, 0);
        acc[1] = __builtin_amdgcn_mfma_f32_16x16x32_bf16(af.v, v1, acc[1], 0, 0, 0);
        acc[2] = __builtin_amdgcn_mfma_f32_16x16x32_bf16(af.v, v2, acc[2], 0, 0, 0);
        acc[3] = __builtin_amdgcn_mfma_f32_16x16x32_bf16(af.v, v3, acc[3], 0, 0, 0);
        dsum   = __builtin_amdgcn_mfma_f32_16x16x32_bf16(af.v, ones, dsum, 0, 0, 0);
    }

    float inv[4];
    #pragma unroll
    for (int r = 0; r < 4; ++r) inv[r] = 1.0f / dsum[r];
    #pragma unroll
    for (int n = 0; n < 4; ++n)
        #pragma unroll
        for (int r = 0; r < 4; ++r) {
            const int io = i0 + wv * 16 + g * 4 + r;
            out[(size_t)(b * NN + io) * NH + h * 64 + n * 16 + l15] =
                acc[n][r] * inv[r];
        }
}

// ---------------------------------------------------------------------------
extern "C" void kernel_launch(void* const* d_in, const int* in_sizes, int n_in,
                              void* d_out, int out_size, void* d_ws, size_t ws_size,
                              hipStream_t stream) {
    const float* h   = (const float*)d_in[0];
    const int*   adj = (const int*)  d_in[1];
    const float* W   = (const float*)d_in[2];
    const float* a   = (const float*)d_in[3];
    float* out = (float*)d_out;

    char* p = (char*)d_ws;
    u16*   hb   = (u16*)p;   p += (size_t)BS * NN * FIN * 2;        // 4 MB
    u16*   WbT  = (u16*)p;   p += (size_t)NH * FIN * 2;             // 256 KB
    u16*   WhT  = (u16*)p;   p += (size_t)BS * HEADS * FO * NN * 2; // 8 MB
    float* WaT  = (float*)p; p += (size_t)16 * FIN * 4;             // 16 KB
    float* esrc = (float*)p; p += (size_t)BS * HEADS * NN * 4;      // 256 KB
    float* edst = (float*)p; p += (size_t)BS * HEADS * NN * 4;      // 256 KB
    u32*   bits = (u32*)p;                                          // 1 MB

    prep_misc<<<9248, 256, 0, stream>>>(h, adj, W, a, hb, WbT, WaT, bits);
    calc_e   <<<(BS * NN) / 4, 256, 0, stream>>>(h, WaT, esrc, edst);
    gemm_whT <<<1024, 256, 0, stream>>>(hb, WbT, WhT);
    attn_pv  <<<1024, 256, 0, stream>>>(bits, WhT, esrc, edst, out);
}

// Round 9
// 53.344 us; speedup vs baseline: 2.0804x; 2.0804x over previous
//
#include <hip/hip_runtime.h>
#include <hip/hip_bf16.h>
#include <math.h>

#define BS 8
#define NN 1024
#define FIN 256
#define HEADS 8
#define FO 64
#define NH (HEADS*FO)   /* 512 */
static constexpr float ALPHA = 0.2f;
static constexpr float LOG2E = 1.4426950408889634f;

typedef short bf16x8 __attribute__((ext_vector_type(8)));
typedef float f32x4  __attribute__((ext_vector_type(4)));
typedef unsigned short u16;
typedef unsigned u32;
typedef u16 u16x4v __attribute__((ext_vector_type(4)));
typedef u16 u16x8v __attribute__((ext_vector_type(8)));

__device__ __forceinline__ u16 f2b(float x) {
    __hip_bfloat16 b = __float2bfloat16(x);
    return *reinterpret_cast<u16*>(&b);
}
__device__ __forceinline__ float fexp2(float x) {
#if __has_builtin(__builtin_amdgcn_exp2f)
    return __builtin_amdgcn_exp2f(x);
#else
    float r; asm("v_exp_f32 %0, %1" : "=v"(r) : "v"(x)); return r;
#endif
}
__device__ __forceinline__ void gload_lds16(const void* g, void* l) {
    __builtin_amdgcn_global_load_lds(
        (const __attribute__((address_space(1))) unsigned int*)g,
        (__attribute__((address_space(3))) unsigned int*)l, 16, 0, 0);
}

// ---------------------------------------------------------------------------
// prep_misc: fused {pack_adj | cvt_h | cvt_wT}. 8192 + 1024 + 32 blocks.
// ---------------------------------------------------------------------------
__global__ __launch_bounds__(256) void prep_misc(const float* __restrict__ h,
                                                 const int* __restrict__ adj,
                                                 const float* __restrict__ W,
                                                 u16* __restrict__ hb,
                                                 u16* __restrict__ WbT,
                                                 u32* __restrict__ bits) {
    const int bid = blockIdx.x;
    const int t = threadIdx.x;
    if (bid < 8192) {
        // ---- pack_adj: 4 elems/lane (int4) + shuffle-assemble ----
        const int lane = t & 63;
        const size_t e0 = ((size_t)bid * 256 + t) * 4;
        const int4 v = *reinterpret_cast<const int4*>(adj + e0);
        u32 x = (v.x ? 1u : 0u) | (v.y ? 2u : 0u) | (v.z ? 4u : 0u) | (v.w ? 8u : 0u);
        {   const u32 r = (u32)__shfl_xor((int)x, 1);
            const int sh = (lane & 1) * 4;  x = (x << sh) | (r << (4 - sh)); }
        {   const u32 r = (u32)__shfl_xor((int)x, 2);
            const int sh = (lane & 2) * 4;  x = (x << sh) | (r << (8 - sh)); }
        {   const u32 r = (u32)__shfl_xor((int)x, 4);
            const int sh = (lane & 4) * 4;  x = (x << sh) | (r << (16 - sh)); }
        if ((lane & 7) == 0) bits[e0 >> 5] = x;
    } else if (bid < 9216) {
        // ---- cvt_h: h f32 -> bf16, 8 elems/thread ----
        const int i = ((bid - 8192) * 256 + t) * 8;
        const float4 v0 = *reinterpret_cast<const float4*>(h + i);
        const float4 v1 = *reinterpret_cast<const float4*>(h + i + 4);
        u16x8v o;
        o[0]=f2b(v0.x); o[1]=f2b(v0.y); o[2]=f2b(v0.z); o[3]=f2b(v0.w);
        o[4]=f2b(v1.x); o[5]=f2b(v1.y); o[6]=f2b(v1.z); o[7]=f2b(v1.w);
        *reinterpret_cast<u16x8v*>(hb + i) = o;
    } else {
        // ---- cvt_wT: W[256][512] -> WbT[512][256] bf16 ----
        __shared__ float T[64][65];
        const int bb = bid - 9216;
        const int hh = bb & 7;
        const int n0 = hh * 64, k0 = (bb >> 3) * 64;
        const int r4 = t >> 6, c = t & 63;
        #pragma unroll
        for (int p = 0; p < 16; ++p) {
            const int r = p * 4 + r4;
            T[r][c] = W[(size_t)(k0 + r) * NH + n0 + c];
        }
        __syncthreads();
        #pragma unroll
        for (int p = 0; p < 16; ++p) {
            const int r = p * 4 + r4;
            WbT[(size_t)(n0 + r) * FIN + k0 + c] = f2b(T[c][r]);
        }
    }
}

// ---------------------------------------------------------------------------
// gemm_whT: Wh = hb @ WbT^T, 64x64 tile, grid 1024, XCD-chunked.
// Epilogue: exact-f32 e_src/e_dst from accumulators (kills calc_e kernel)
// + transposed bf16 WhT store via LDS bounce.
// ---------------------------------------------------------------------------
__global__ __launch_bounds__(256) void gemm_whT(const u16* __restrict__ hb,
                                                const u16* __restrict__ WbT,
                                                const float* __restrict__ avec,
                                                u16* __restrict__ WhT,
                                                float* __restrict__ esrc,
                                                float* __restrict__ edst) {
    __shared__ u16 Al[2][64 * 64];
    __shared__ u16 Bl[2][64 * 64];
    const int t = threadIdx.x, wv = t >> 6, lane = t & 63;
    const int g = lane >> 4, l15 = lane & 15;
    const int lid = (blockIdx.x & 7) * 128 + (blockIdx.x >> 3);
    const int m0 = (lid >> 3) * 64;
    const int h  = lid & 7;
    const int lr = lane >> 3;
    const int sch = (lane & 7) ^ lr;
    const int bh = (m0 >> 10) * HEADS + h;

    f32x4 acc[4] = {};

    auto stageA = [&](int buf, int k0) {
        #pragma unroll
        for (int c = 0; c < 2; ++c) {
            const int rowb = wv * 16 + c * 8;
            gload_lds16(hb + (size_t)(m0 + rowb + lr) * FIN + k0 + sch * 8,
                        &Al[buf][rowb * 64]);
        }
    };
    auto stageB = [&](int buf, int k0) {
        #pragma unroll
        for (int c = 0; c < 2; ++c) {
            const int rowb = wv * 16 + c * 8;
            gload_lds16(WbT + (size_t)(h * 64 + rowb + lr) * FIN + k0 + sch * 8,
                        &Bl[buf][rowb * 64]);
        }
    };

    stageA(0, 0); stageB(0, 0);
    __syncthreads();
    for (int kt = 0; kt < 4; ++kt) {
        const int buf = kt & 1;
        if (kt < 3) { stageA(buf ^ 1, (kt + 1) * 64); stageB(buf ^ 1, (kt + 1) * 64); }
        #pragma unroll
        for (int ks = 0; ks < 2; ++ks) {
            const int ch = (ks * 4 + g) ^ (l15 & 7);
            const bf16x8 afr = *reinterpret_cast<const bf16x8*>(
                &Al[buf][(wv * 16 + l15) * 64 + ch * 8]);
            #pragma unroll
            for (int n = 0; n < 4; ++n) {
                const bf16x8 bfr = *reinterpret_cast<const bf16x8*>(
                    &Bl[buf][(n * 16 + l15) * 64 + ch * 8]);
                acc[n] = __builtin_amdgcn_mfma_f32_16x16x32_bf16(afr, bfr, acc[n], 0, 0, 0);
            }
        }
        __syncthreads();
    }

    // ---- e epilogue (exact f32, exp2 domain): es/ed = sum_f acc*a*log2e ----
    {
        float as_[4], ad_[4];
        #pragma unroll
        for (int n = 0; n < 4; ++n) {
            as_[n] = avec[h * 128 + n * 16 + l15] * LOG2E;
            ad_[n] = avec[h * 128 + 64 + n * 16 + l15] * LOG2E;
        }
        #pragma unroll
        for (int r = 0; r < 4; ++r) {
            float ps = acc[0][r] * as_[0] + acc[1][r] * as_[1]
                     + acc[2][r] * as_[2] + acc[3][r] * as_[3];
            float pd = acc[0][r] * ad_[0] + acc[1][r] * ad_[1]
                     + acc[2][r] * ad_[2] + acc[3][r] * ad_[3];
            #pragma unroll
            for (int off = 1; off < 16; off <<= 1) {
                ps += __shfl_xor(ps, off);
                pd += __shfl_xor(pd, off);
            }
            if (l15 == 0) {
                const int i = (m0 + wv * 16 + g * 4 + r) & (NN - 1);
                esrc[(size_t)bh * NN + i] = ps;
                edst[(size_t)bh * NN + i] = pd;
            }
        }
    }

    // ---- WhT store via LDS bounce (coalesced) ----
    u16* scr = &Al[0][0];
    #pragma unroll
    for (int n = 0; n < 4; ++n) {
        u16x4v pk;
        #pragma unroll
        for (int r = 0; r < 4; ++r) pk[r] = f2b(acc[n][r]);
        *reinterpret_cast<u16x4v*>(&scr[(n * 16 + l15) * 72 + wv * 16 + g * 4]) = pk;
    }
    __syncthreads();
    const int il0 = m0 & (NN - 1);
    const int f = t >> 2, q = t & 3;
    const u16x8v v0 = *reinterpret_cast<const u16x8v*>(&scr[f * 72 + q * 16]);
    const u16x8v v1 = *reinterpret_cast<const u16x8v*>(&scr[f * 72 + q * 16 + 8]);
    u16* dst = &WhT[((size_t)bh * 64 + f) * NN + il0 + q * 16];
    *reinterpret_cast<u16x8v*>(dst)     = v0;
    *reinterpret_cast<u16x8v*>(dst + 8) = v1;
}

// ---------------------------------------------------------------------------
// attn_pv v4: hybrid. V tile in LDS (coalesced gload_lds, shared by the
// block's 2 waves); ed/bits streamed via registers from global (L1/L2-hit,
// 1-deep prefetch). 128 thr / 2 waves / 32 rows, grid 2048 -> 8 independent
// blocks/CU so barrier drains overlap. Denominator via mfma(P, ones).
// ---------------------------------------------------------------------------
__global__ __launch_bounds__(128, 4) void attn_pv(const u32* __restrict__ bits,
                                                  const u16* __restrict__ WhT,
                                                  const float* __restrict__ esrc,
                                                  const float* __restrict__ edst,
                                                  float* __restrict__ out) {
    __shared__ u16 Bs[2][64 * 64];             // 16 KB, V tile dbuf
    const int t = threadIdx.x, wv = t >> 6, lane = t & 63;
    const int g = lane >> 4, l15 = lane & 15;
    const int lr = lane >> 3, sch = (lane & 7) ^ lr;

    // XCD chunk: 256 consecutive lids (one batch) per XCD
    const int lid = (blockIdx.x & 7) * 256 + (blockIdx.x >> 3);
    const int it = lid & 31, h = (lid >> 5) & 7, b = lid >> 8;
    const int i0 = it * 32;
    const int bh = b * HEADS + h;
    const int rowi = i0 + wv * 16 + l15;

    const float es = esrc[(size_t)bh * NN + rowi];
    const u16*  whb = WhT + (size_t)bh * 64 * NN;
    const float* ed = edst + (size_t)bh * NN + 8 * g;
    const u32*  bitrow = bits + (size_t)(b * NN + rowi) * 32;

    auto stageB = [&](int buf, int j0) {
        #pragma unroll
        for (int c = 0; c < 4; ++c) {
            const int fb = wv * 32 + c * 8;
            gload_lds16(whb + (size_t)(fb + lr) * NN + j0 + sch * 8,
                        &Bs[buf][fb * 64]);
        }
    };

    stageB(0, 0);
    // register prefetch of step 0 operands (global, L1/L2-resident)
    float4 pe0 = *(const float4*)(ed);
    float4 pe1 = *(const float4*)(ed + 4);
    u32    pw  = bitrow[0];
    __syncthreads();

    f32x4 acc[4] = {};
    f32x4 dsum = {};
    bf16x8 ones;
    #pragma unroll
    for (int q = 0; q < 8; ++q) ones[q] = (short)0x3F80;   // bf16(1.0)

    for (int tt = 0; tt < 16; ++tt) {
        const int buf = tt & 1;
        if (tt < 15) stageB(buf ^ 1, (tt + 1) * 64);
        #pragma unroll
        for (int ks = 0; ks < 2; ++ks) {
            const int s = tt * 2 + ks;
            const float4 e0 = pe0, e1 = pe1;
            const u32 word = pw;
            if (s < 31) {                      // prefetch step s+1
                pe0 = *(const float4*)(ed + (s + 1) * 32);
                pe1 = *(const float4*)(ed + (s + 1) * 32 + 4);
                pw  = bitrow[s + 1];
            }
            // B fragments early: ds latency hides under p-gen
            const int chb = ((ks * 4 + g) ^ (l15 & 7)) * 8;
            const bf16x8 v0 = *(const bf16x8*)(&Bs[buf][(0 * 16 + l15) * 64 + chb]);
            const bf16x8 v1 = *(const bf16x8*)(&Bs[buf][(1 * 16 + l15) * 64 + chb]);
            const bf16x8 v2 = *(const bf16x8*)(&Bs[buf][(2 * 16 + l15) * 64 + chb]);
            const bf16x8 v3 = *(const bf16x8*)(&Bs[buf][(3 * 16 + l15) * 64 + chb]);

            const u32 byte_ = (word >> (8 * g)) & 0xffu;
            float ps[8];
            {
                float sv;
                sv = es + e0.x; sv = fmaxf(sv, ALPHA * sv); sv = (byte_ & 1u)        ? sv : -1e30f; ps[0] = fexp2(sv);
                sv = es + e0.y; sv = fmaxf(sv, ALPHA * sv); sv = ((byte_ >> 1) & 1u) ? sv : -1e30f; ps[1] = fexp2(sv);
                sv = es + e0.z; sv = fmaxf(sv, ALPHA * sv); sv = ((byte_ >> 2) & 1u) ? sv : -1e30f; ps[2] = fexp2(sv);
                sv = es + e0.w; sv = fmaxf(sv, ALPHA * sv); sv = ((byte_ >> 3) & 1u) ? sv : -1e30f; ps[3] = fexp2(sv);
                sv = es + e1.x; sv = fmaxf(sv, ALPHA * sv); sv = ((byte_ >> 4) & 1u) ? sv : -1e30f; ps[4] = fexp2(sv);
                sv = es + e1.y; sv = fmaxf(sv, ALPHA * sv); sv = ((byte_ >> 5) & 1u) ? sv : -1e30f; ps[5] = fexp2(sv);
                sv = es + e1.z; sv = fmaxf(sv, ALPHA * sv); sv = ((byte_ >> 6) & 1u) ? sv : -1e30f; ps[6] = fexp2(sv);
                sv = es + e1.w; sv = fmaxf(sv, ALPHA * sv); sv = ((byte_ >> 7) & 1u) ? sv : -1e30f; ps[7] = fexp2(sv);
            }
            union { u32 u[4]; bf16x8 v; } af;
            #pragma unroll
            for (int qp = 0; qp < 4; ++qp) {
                union { __hip_bfloat162 b2; u32 w; } cv;
                cv.b2 = __float22bfloat162_rn(make_float2(ps[2*qp], ps[2*qp+1]));
                af.u[qp] = cv.w;
            }
            acc[0] = __builtin_amdgcn_mfma_f32_16x16x32_bf16(af.v, v0, acc[0], 0, 0, 0);
            acc[1] = __builtin_amdgcn_mfma_f32_16x16x32_bf16(af.v, v1, acc[1], 0, 0, 0);
            acc[2] = __builtin_amdgcn_mfma_f32_16x16x32_bf16(af.v, v2, acc[2], 0, 0, 0);
            acc[3] = __builtin_amdgcn_mfma_f32_16x16x32_bf16(af.v, v3, acc[3], 0, 0, 0);
            dsum   = __builtin_amdgcn_mfma_f32_16x16x32_bf16(af.v, ones, dsum, 0, 0, 0);
        }
        if (tt < 15) __syncthreads();
    }

    float inv[4];
    #pragma unroll
    for (int r = 0; r < 4; ++r) inv[r] = 1.0f / dsum[r];
    #pragma unroll
    for (int n = 0; n < 4; ++n)
        #pragma unroll
        for (int r = 0; r < 4; ++r) {
            const int io = i0 + wv * 16 + g * 4 + r;
            out[(size_t)(b * NN + io) * NH + h * 64 + n * 16 + l15] =
                acc[n][r] * inv[r];
        }
}

// ---------------------------------------------------------------------------
extern "C" void kernel_launch(void* const* d_in, const int* in_sizes, int n_in,
                              void* d_out, int out_size, void* d_ws, size_t ws_size,
                              hipStream_t stream) {
    const float* h   = (const float*)d_in[0];
    const int*   adj = (const int*)  d_in[1];
    const float* W   = (const float*)d_in[2];
    const float* a   = (const float*)d_in[3];
    float* out = (float*)d_out;

    char* p = (char*)d_ws;
    u16*   hb   = (u16*)p;   p += (size_t)BS * NN * FIN * 2;        // 4 MB
    u16*   WbT  = (u16*)p;   p += (size_t)NH * FIN * 2;             // 256 KB
    u16*   WhT  = (u16*)p;   p += (size_t)BS * HEADS * FO * NN * 2; // 8 MB
    float* esrc = (float*)p; p += (size_t)BS * HEADS * NN * 4;      // 256 KB
    float* edst = (float*)p; p += (size_t)BS * HEADS * NN * 4;      // 256 KB
    u32*   bits = (u32*)p;                                          // 1 MB

    prep_misc<<<9248, 256, 0, stream>>>(h, adj, W, hb, WbT, bits);
    gemm_whT <<<1024, 256, 0, stream>>>(hb, WbT, a, WhT, esrc, edst);
    attn_pv  <<<2048, 128, 0, stream>>>(bits, WhT, esrc, edst, out);
}

// Round 10
// 51.350 us; speedup vs baseline: 2.1612x; 1.0388x over previous
//
#include <hip/hip_runtime.h>
#include <hip/hip_bf16.h>
#include <math.h>

#define BS 8
#define NN 1024
#define FIN 256
#define HEADS 8
#define FO 64
#define NH (HEADS*FO)   /* 512 */
static constexpr float ALPHA = 0.2f;
static constexpr float LOG2E = 1.4426950408889634f;

typedef short bf16x8 __attribute__((ext_vector_type(8)));
typedef float f32x4  __attribute__((ext_vector_type(4)));
typedef unsigned short u16;
typedef unsigned u32;
typedef u16 u16x4v __attribute__((ext_vector_type(4)));
typedef u16 u16x8v __attribute__((ext_vector_type(8)));

__device__ __forceinline__ u16 f2b(float x) {
    __hip_bfloat16 b = __float2bfloat16(x);
    return *reinterpret_cast<u16*>(&b);
}
__device__ __forceinline__ float fexp2(float x) {
#if __has_builtin(__builtin_amdgcn_exp2f)
    return __builtin_amdgcn_exp2f(x);
#else
    float r; asm("v_exp_f32 %0, %1" : "=v"(r) : "v"(x)); return r;
#endif
}
__device__ __forceinline__ void gload_lds16(const void* g, void* l) {
    __builtin_amdgcn_global_load_lds(
        (const __attribute__((address_space(1))) unsigned int*)g,
        (__attribute__((address_space(3))) unsigned int*)l, 16, 0, 0);
}

// ---------------------------------------------------------------------------
// prep_misc: fused {pack_adj | cvt_h | cvt_wT}. 8192 + 1024 + 32 blocks.
// ---------------------------------------------------------------------------
__global__ __launch_bounds__(256) void prep_misc(const float* __restrict__ h,
                                                 const int* __restrict__ adj,
                                                 const float* __restrict__ W,
                                                 u16* __restrict__ hb,
                                                 u16* __restrict__ WbT,
                                                 u32* __restrict__ bits) {
    const int bid = blockIdx.x;
    const int t = threadIdx.x;
    if (bid < 8192) {
        const int lane = t & 63;
        const size_t e0 = ((size_t)bid * 256 + t) * 4;
        const int4 v = *reinterpret_cast<const int4*>(adj + e0);
        u32 x = (v.x ? 1u : 0u) | (v.y ? 2u : 0u) | (v.z ? 4u : 0u) | (v.w ? 8u : 0u);
        {   const u32 r = (u32)__shfl_xor((int)x, 1);
            const int sh = (lane & 1) * 4;  x = (x << sh) | (r << (4 - sh)); }
        {   const u32 r = (u32)__shfl_xor((int)x, 2);
            const int sh = (lane & 2) * 4;  x = (x << sh) | (r << (8 - sh)); }
        {   const u32 r = (u32)__shfl_xor((int)x, 4);
            const int sh = (lane & 4) * 4;  x = (x << sh) | (r << (16 - sh)); }
        if ((lane & 7) == 0) bits[e0 >> 5] = x;
    } else if (bid < 9216) {
        const int i = ((bid - 8192) * 256 + t) * 8;
        const float4 v0 = *reinterpret_cast<const float4*>(h + i);
        const float4 v1 = *reinterpret_cast<const float4*>(h + i + 4);
        u16x8v o;
        o[0]=f2b(v0.x); o[1]=f2b(v0.y); o[2]=f2b(v0.z); o[3]=f2b(v0.w);
        o[4]=f2b(v1.x); o[5]=f2b(v1.y); o[6]=f2b(v1.z); o[7]=f2b(v1.w);
        *reinterpret_cast<u16x8v*>(hb + i) = o;
    } else {
        __shared__ float T[64][65];
        const int bb = bid - 9216;
        const int hh = bb & 7;
        const int n0 = hh * 64, k0 = (bb >> 3) * 64;
        const int r4 = t >> 6, c = t & 63;
        #pragma unroll
        for (int p = 0; p < 16; ++p) {
            const int r = p * 4 + r4;
            T[r][c] = W[(size_t)(k0 + r) * NH + n0 + c];
        }
        __syncthreads();
        #pragma unroll
        for (int p = 0; p < 16; ++p) {
            const int r = p * 4 + r4;
            WbT[(size_t)(n0 + r) * FIN + k0 + c] = f2b(T[c][r]);
        }
    }
}

// ---------------------------------------------------------------------------
// gemm_whT: Wh = hb @ WbT^T, 64x64 tile, grid 1024, XCD-chunked.
// Epilogue: exact-f32 e_src/e_dst from accumulators + transposed bf16 WhT.
// ---------------------------------------------------------------------------
__global__ __launch_bounds__(256) void gemm_whT(const u16* __restrict__ hb,
                                                const u16* __restrict__ WbT,
                                                const float* __restrict__ avec,
                                                u16* __restrict__ WhT,
                                                float* __restrict__ esrc,
                                                float* __restrict__ edst) {
    __shared__ u16 Al[2][64 * 64];
    __shared__ u16 Bl[2][64 * 64];
    const int t = threadIdx.x, wv = t >> 6, lane = t & 63;
    const int g = lane >> 4, l15 = lane & 15;
    const int lid = (blockIdx.x & 7) * 128 + (blockIdx.x >> 3);
    const int m0 = (lid >> 3) * 64;
    const int h  = lid & 7;
    const int lr = lane >> 3;
    const int sch = (lane & 7) ^ lr;
    const int bh = (m0 >> 10) * HEADS + h;

    f32x4 acc[4] = {};

    auto stageA = [&](int buf, int k0) {
        #pragma unroll
        for (int c = 0; c < 2; ++c) {
            const int rowb = wv * 16 + c * 8;
            gload_lds16(hb + (size_t)(m0 + rowb + lr) * FIN + k0 + sch * 8,
                        &Al[buf][rowb * 64]);
        }
    };
    auto stageB = [&](int buf, int k0) {
        #pragma unroll
        for (int c = 0; c < 2; ++c) {
            const int rowb = wv * 16 + c * 8;
            gload_lds16(WbT + (size_t)(h * 64 + rowb + lr) * FIN + k0 + sch * 8,
                        &Bl[buf][rowb * 64]);
        }
    };

    stageA(0, 0); stageB(0, 0);
    __syncthreads();
    for (int kt = 0; kt < 4; ++kt) {
        const int buf = kt & 1;
        if (kt < 3) { stageA(buf ^ 1, (kt + 1) * 64); stageB(buf ^ 1, (kt + 1) * 64); }
        #pragma unroll
        for (int ks = 0; ks < 2; ++ks) {
            const int ch = (ks * 4 + g) ^ (l15 & 7);
            const bf16x8 afr = *reinterpret_cast<const bf16x8*>(
                &Al[buf][(wv * 16 + l15) * 64 + ch * 8]);
            #pragma unroll
            for (int n = 0; n < 4; ++n) {
                const bf16x8 bfr = *reinterpret_cast<const bf16x8*>(
                    &Bl[buf][(n * 16 + l15) * 64 + ch * 8]);
                acc[n] = __builtin_amdgcn_mfma_f32_16x16x32_bf16(afr, bfr, acc[n], 0, 0, 0);
            }
        }
        __syncthreads();
    }

    // ---- e epilogue (exact f32, exp2 domain) ----
    {
        float as_[4], ad_[4];
        #pragma unroll
        for (int n = 0; n < 4; ++n) {
            as_[n] = avec[h * 128 + n * 16 + l15] * LOG2E;
            ad_[n] = avec[h * 128 + 64 + n * 16 + l15] * LOG2E;
        }
        #pragma unroll
        for (int r = 0; r < 4; ++r) {
            float ps = acc[0][r] * as_[0] + acc[1][r] * as_[1]
                     + acc[2][r] * as_[2] + acc[3][r] * as_[3];
            float pd = acc[0][r] * ad_[0] + acc[1][r] * ad_[1]
                     + acc[2][r] * ad_[2] + acc[3][r] * ad_[3];
            #pragma unroll
            for (int off = 1; off < 16; off <<= 1) {
                ps += __shfl_xor(ps, off);
                pd += __shfl_xor(pd, off);
            }
            if (l15 == 0) {
                const int i = (m0 + wv * 16 + g * 4 + r) & (NN - 1);
                esrc[(size_t)bh * NN + i] = ps;
                edst[(size_t)bh * NN + i] = pd;
            }
        }
    }

    // ---- WhT store via LDS bounce (coalesced) ----
    u16* scr = &Al[0][0];
    #pragma unroll
    for (int n = 0; n < 4; ++n) {
        u16x4v pk;
        #pragma unroll
        for (int r = 0; r < 4; ++r) pk[r] = f2b(acc[n][r]);
        *reinterpret_cast<u16x4v*>(&scr[(n * 16 + l15) * 72 + wv * 16 + g * 4]) = pk;
    }
    __syncthreads();
    const int il0 = m0 & (NN - 1);
    const int f = t >> 2, q = t & 3;
    const u16x8v v0 = *reinterpret_cast<const u16x8v*>(&scr[f * 72 + q * 16]);
    const u16x8v v1 = *reinterpret_cast<const u16x8v*>(&scr[f * 72 + q * 16 + 8]);
    u16* dst = &WhT[((size_t)bh * 64 + f) * NN + il0 + q * 16];
    *reinterpret_cast<u16x8v*>(dst)     = v0;
    *reinterpret_cast<u16x8v*>(dst + 8) = v1;
}

// ---------------------------------------------------------------------------
// attn_pv v5: r9 hybrid + (T4) counted-vmcnt raw barrier, 2-deep ed/bits
// register prefetch, (T5) setprio around the MFMA cluster.
// 128 thr / 2 waves / 32 rows, grid 2048, XCD-chunked.
// ---------------------------------------------------------------------------
__global__ __launch_bounds__(128, 4) void attn_pv(const u32* __restrict__ bits,
                                                  const u16* __restrict__ WhT,
                                                  const float* __restrict__ esrc,
                                                  const float* __restrict__ edst,
                                                  float* __restrict__ out) {
    __shared__ u16 Bs[2][64 * 64];             // 16 KB, V tile dbuf
    const int t = threadIdx.x, wv = t >> 6, lane = t & 63;
    const int g = lane >> 4, l15 = lane & 15;
    const int lr = lane >> 3, sch = (lane & 7) ^ lr;

    const int lid = (blockIdx.x & 7) * 256 + (blockIdx.x >> 3);
    const int it = lid & 31, h = (lid >> 5) & 7, b = lid >> 8;
    const int i0 = it * 32;
    const int bh = b * HEADS + h;
    const int rowi = i0 + wv * 16 + l15;

    const float es = esrc[(size_t)bh * NN + rowi];
    const u16*  whb = WhT + (size_t)bh * 64 * NN;
    const float* ed = edst + (size_t)bh * NN + 8 * g;
    const u32*  bitrow = bits + (size_t)(b * NN + rowi) * 32;

    auto stageB = [&](int buf, int j0) {
        #pragma unroll
        for (int c = 0; c < 4; ++c) {
            const int fb = wv * 32 + c * 8;
            gload_lds16(whb + (size_t)(fb + lr) * NN + j0 + sch * 8,
                        &Bs[buf][fb * 64]);
        }
    };

    stageB(0, 0);
    // 2-deep register prefetch slots (slot = parity of step s)
    float4 peA[2], peB[2];
    u32    pwS[2];
    #pragma unroll
    for (int s = 0; s < 2; ++s) {
        peA[s] = *(const float4*)(ed + s * 32);
        peB[s] = *(const float4*)(ed + s * 32 + 4);
        pwS[s] = bitrow[s];
    }
    __syncthreads();

    f32x4 acc[4] = {};
    f32x4 dsum = {};
    bf16x8 ones;
    #pragma unroll
    for (int q = 0; q < 8; ++q) ones[q] = (short)0x3F80;   // bf16(1.0)

    for (int tt = 0; tt < 16; ++tt) {
        const int buf = tt & 1;
        const bool more = (tt < 15);
        if (more) {
            stageB(buf ^ 1, (tt + 1) * 64);
            // pin ordering: keep later ed/bits loads AFTER the 4 stage loads
            asm volatile("" ::: "memory");
        }
        #pragma unroll
        for (int ks = 0; ks < 2; ++ks) {
            const int s = tt * 2 + ks;
            const float4 e0 = peA[ks], e1 = peB[ks];
            const u32 word = pwS[ks];
            if (more) {                        // prefetch step s+2 (same slot)
                peA[ks] = *(const float4*)(ed + (s + 2) * 32);
                peB[ks] = *(const float4*)(ed + (s + 2) * 32 + 4);
                pwS[ks] = bitrow[s + 2];
            }
            // B fragments early: ds latency hides under p-gen
            const int chb = ((ks * 4 + g) ^ (l15 & 7)) * 8;
            const bf16x8 v0 = *(const bf16x8*)(&Bs[buf][(0 * 16 + l15) * 64 + chb]);
            const bf16x8 v1 = *(const bf16x8*)(&Bs[buf][(1 * 16 + l15) * 64 + chb]);
            const bf16x8 v2 = *(const bf16x8*)(&Bs[buf][(2 * 16 + l15) * 64 + chb]);
            const bf16x8 v3 = *(const bf16x8*)(&Bs[buf][(3 * 16 + l15) * 64 + chb]);

            const u32 byte_ = (word >> (8 * g)) & 0xffu;
            float ps[8];
            {
                float sv;
                sv = es + e0.x; sv = fmaxf(sv, ALPHA * sv); sv = (byte_ & 1u)        ? sv : -1e30f; ps[0] = fexp2(sv);
                sv = es + e0.y; sv = fmaxf(sv, ALPHA * sv); sv = ((byte_ >> 1) & 1u) ? sv : -1e30f; ps[1] = fexp2(sv);
                sv = es + e0.z; sv = fmaxf(sv, ALPHA * sv); sv = ((byte_ >> 2) & 1u) ? sv : -1e30f; ps[2] = fexp2(sv);
                sv = es + e0.w; sv = fmaxf(sv, ALPHA * sv); sv = ((byte_ >> 3) & 1u) ? sv : -1e30f; ps[3] = fexp2(sv);
                sv = es + e1.x; sv = fmaxf(sv, ALPHA * sv); sv = ((byte_ >> 4) & 1u) ? sv : -1e30f; ps[4] = fexp2(sv);
                sv = es + e1.y; sv = fmaxf(sv, ALPHA * sv); sv = ((byte_ >> 5) & 1u) ? sv : -1e30f; ps[5] = fexp2(sv);
                sv = es + e1.z; sv = fmaxf(sv, ALPHA * sv); sv = ((byte_ >> 6) & 1u) ? sv : -1e30f; ps[6] = fexp2(sv);
                sv = es + e1.w; sv = fmaxf(sv, ALPHA * sv); sv = ((byte_ >> 7) & 1u) ? sv : -1e30f; ps[7] = fexp2(sv);
            }
            union { u32 u[4]; bf16x8 v; } af;
            #pragma unroll
            for (int qp = 0; qp < 4; ++qp) {
                union { __hip_bfloat162 b2; u32 w; } cv;
                cv.b2 = __float22bfloat162_rn(make_float2(ps[2*qp], ps[2*qp+1]));
                af.u[qp] = cv.w;
            }
            __builtin_amdgcn_s_setprio(1);
            acc[0] = __builtin_amdgcn_mfma_f32_16x16x32_bf16(af.v, v0, acc[0], 0, 0, 0);
            acc[1] = __builtin_amdgcn_mfma_f32_16x16x32_bf16(af.v, v1, acc[1], 0, 0, 0);
            acc[2] = __builtin_amdgcn_mfma_f32_16x16x32_bf16(af.v, v2, acc[2], 0, 0, 0);
            acc[3] = __builtin_amdgcn_mfma_f32_16x16x32_bf16(af.v, v3, acc[3], 0, 0, 0);
            dsum   = __builtin_amdgcn_mfma_f32_16x16x32_bf16(af.v, ones, dsum, 0, 0, 0);
            __builtin_amdgcn_s_setprio(0);
        }
        if (more) {
            // stage(tt+1)'s 4 loads are the only VMEM older than the 6
            // ed/bits prefetches issued this tile -> vmcnt(6) ensures the
            // stage landed without draining the prefetches (T4).
            asm volatile("s_waitcnt vmcnt(6)" ::: "memory");
            __builtin_amdgcn_s_barrier();
        }
    }

    float inv[4];
    #pragma unroll
    for (int r = 0; r < 4; ++r) inv[r] = 1.0f / dsum[r];
    #pragma unroll
    for (int n = 0; n < 4; ++n)
        #pragma unroll
        for (int r = 0; r < 4; ++r) {
            const int io = i0 + wv * 16 + g * 4 + r;
            out[(size_t)(b * NN + io) * NH + h * 64 + n * 16 + l15] =
                acc[n][r] * inv[r];
        }
}

// ---------------------------------------------------------------------------
extern "C" void kernel_launch(void* const* d_in, const int* in_sizes, int n_in,
                              void* d_out, int out_size, void* d_ws, size_t ws_size,
                              hipStream_t stream) {
    const float* h   = (const float*)d_in[0];
    const int*   adj = (const int*)  d_in[1];
    const float* W   = (const float*)d_in[2];
    const float* a   = (const float*)d_in[3];
    float* out = (float*)d_out;

    char* p = (char*)d_ws;
    u16*   hb   = (u16*)p;   p += (size_t)BS * NN * FIN * 2;        // 4 MB
    u16*   WbT  = (u16*)p;   p += (size_t)NH * FIN * 2;             // 256 KB
    u16*   WhT  = (u16*)p;   p += (size_t)BS * HEADS * FO * NN * 2; // 8 MB
    float* esrc = (float*)p; p += (size_t)BS * HEADS * NN * 4;      // 256 KB
    float* edst = (float*)p; p += (size_t)BS * HEADS * NN * 4;      // 256 KB
    u32*   bits = (u32*)p;                                          // 1 MB

    prep_misc<<<9248, 256, 0, stream>>>(h, adj, W, hb, WbT, bits);
    gemm_whT <<<1024, 256, 0, stream>>>(hb, WbT, a, WhT, esrc, edst);
    attn_pv  <<<2048, 128, 0, stream>>>(bits, WhT, esrc, edst, out);
}

// Round 11
// 50.301 us; speedup vs baseline: 2.2063x; 1.0209x over previous
//
#include <hip/hip_runtime.h>
#include <hip/hip_bf16.h>
#include <math.h>

#define BS 8
#define NN 1024
#define FIN 256
#define HEADS 8
#define FO 64
#define NH (HEADS*FO)   /* 512 */
static constexpr float ALPHA = 0.2f;
static constexpr float LOG2E = 1.4426950408889634f;

typedef short bf16x8 __attribute__((ext_vector_type(8)));
typedef float f32x4  __attribute__((ext_vector_type(4)));
typedef unsigned short u16;
typedef unsigned u32;
typedef u16 u16x4v __attribute__((ext_vector_type(4)));
typedef u16 u16x8v __attribute__((ext_vector_type(8)));

__device__ __forceinline__ u16 f2b(float x) {
    __hip_bfloat16 b = __float2bfloat16(x);
    return *reinterpret_cast<u16*>(&b);
}
__device__ __forceinline__ float fexp2(float x) {
#if __has_builtin(__builtin_amdgcn_exp2f)
    return __builtin_amdgcn_exp2f(x);
#else
    float r; asm("v_exp_f32 %0, %1" : "=v"(r) : "v"(x)); return r;
#endif
}
__device__ __forceinline__ void gload_lds16(const void* g, void* l) {
    __builtin_amdgcn_global_load_lds(
        (const __attribute__((address_space(1))) unsigned int*)g,
        (__attribute__((address_space(3))) unsigned int*)l, 16, 0, 0);
}

// ---------------------------------------------------------------------------
// prep_misc: fused {pack_adj | cvt_h | cvt_wT}. 8192 + 1024 + 32 blocks.
// ---------------------------------------------------------------------------
__global__ __launch_bounds__(256) void prep_misc(const float* __restrict__ h,
                                                 const int* __restrict__ adj,
                                                 const float* __restrict__ W,
                                                 u16* __restrict__ hb,
                                                 u16* __restrict__ WbT,
                                                 u32* __restrict__ bits) {
    const int bid = blockIdx.x;
    const int t = threadIdx.x;
    if (bid < 8192) {
        const int lane = t & 63;
        const size_t e0 = ((size_t)bid * 256 + t) * 4;
        const int4 v = *reinterpret_cast<const int4*>(adj + e0);
        u32 x = (v.x ? 1u : 0u) | (v.y ? 2u : 0u) | (v.z ? 4u : 0u) | (v.w ? 8u : 0u);
        {   const u32 r = (u32)__shfl_xor((int)x, 1);
            const int sh = (lane & 1) * 4;  x = (x << sh) | (r << (4 - sh)); }
        {   const u32 r = (u32)__shfl_xor((int)x, 2);
            const int sh = (lane & 2) * 4;  x = (x << sh) | (r << (8 - sh)); }
        {   const u32 r = (u32)__shfl_xor((int)x, 4);
            const int sh = (lane & 4) * 4;  x = (x << sh) | (r << (16 - sh)); }
        if ((lane & 7) == 0) bits[e0 >> 5] = x;
    } else if (bid < 9216) {
        const int i = ((bid - 8192) * 256 + t) * 8;
        const float4 v0 = *reinterpret_cast<const float4*>(h + i);
        const float4 v1 = *reinterpret_cast<const float4*>(h + i + 4);
        u16x8v o;
        o[0]=f2b(v0.x); o[1]=f2b(v0.y); o[2]=f2b(v0.z); o[3]=f2b(v0.w);
        o[4]=f2b(v1.x); o[5]=f2b(v1.y); o[6]=f2b(v1.z); o[7]=f2b(v1.w);
        *reinterpret_cast<u16x8v*>(hb + i) = o;
    } else {
        __shared__ float T[64][65];
        const int bb = bid - 9216;
        const int hh = bb & 7;
        const int n0 = hh * 64, k0 = (bb >> 3) * 64;
        const int r4 = t >> 6, c = t & 63;
        #pragma unroll
        for (int p = 0; p < 16; ++p) {
            const int r = p * 4 + r4;
            T[r][c] = W[(size_t)(k0 + r) * NH + n0 + c];
        }
        __syncthreads();
        #pragma unroll
        for (int p = 0; p < 16; ++p) {
            const int r = p * 4 + r4;
            WbT[(size_t)(n0 + r) * FIN + k0 + c] = f2b(T[c][r]);
        }
    }
}

// ---------------------------------------------------------------------------
// gemm_whT: Wh = hb @ WbT^T, 64x64 tile, grid 1024, XCD-chunked.
// Epilogue: exact-f32 e_src/e_dst from accumulators + transposed bf16 WhT.
// ---------------------------------------------------------------------------
__global__ __launch_bounds__(256) void gemm_whT(const u16* __restrict__ hb,
                                                const u16* __restrict__ WbT,
                                                const float* __restrict__ avec,
                                                u16* __restrict__ WhT,
                                                float* __restrict__ esrc,
                                                float* __restrict__ edst) {
    __shared__ u16 Al[2][64 * 64];
    __shared__ u16 Bl[2][64 * 64];
    const int t = threadIdx.x, wv = t >> 6, lane = t & 63;
    const int g = lane >> 4, l15 = lane & 15;
    const int lid = (blockIdx.x & 7) * 128 + (blockIdx.x >> 3);
    const int m0 = (lid >> 3) * 64;
    const int h  = lid & 7;
    const int lr = lane >> 3;
    const int sch = (lane & 7) ^ lr;
    const int bh = (m0 >> 10) * HEADS + h;

    f32x4 acc[4] = {};

    auto stageA = [&](int buf, int k0) {
        #pragma unroll
        for (int c = 0; c < 2; ++c) {
            const int rowb = wv * 16 + c * 8;
            gload_lds16(hb + (size_t)(m0 + rowb + lr) * FIN + k0 + sch * 8,
                        &Al[buf][rowb * 64]);
        }
    };
    auto stageB = [&](int buf, int k0) {
        #pragma unroll
        for (int c = 0; c < 2; ++c) {
            const int rowb = wv * 16 + c * 8;
            gload_lds16(WbT + (size_t)(h * 64 + rowb + lr) * FIN + k0 + sch * 8,
                        &Bl[buf][rowb * 64]);
        }
    };

    stageA(0, 0); stageB(0, 0);
    __syncthreads();
    for (int kt = 0; kt < 4; ++kt) {
        const int buf = kt & 1;
        if (kt < 3) { stageA(buf ^ 1, (kt + 1) * 64); stageB(buf ^ 1, (kt + 1) * 64); }
        #pragma unroll
        for (int ks = 0; ks < 2; ++ks) {
            const int ch = (ks * 4 + g) ^ (l15 & 7);
            const bf16x8 afr = *reinterpret_cast<const bf16x8*>(
                &Al[buf][(wv * 16 + l15) * 64 + ch * 8]);
            #pragma unroll
            for (int n = 0; n < 4; ++n) {
                const bf16x8 bfr = *reinterpret_cast<const bf16x8*>(
                    &Bl[buf][(n * 16 + l15) * 64 + ch * 8]);
                acc[n] = __builtin_amdgcn_mfma_f32_16x16x32_bf16(afr, bfr, acc[n], 0, 0, 0);
            }
        }
        __syncthreads();
    }

    // ---- e epilogue (exact f32, exp2 domain) ----
    {
        float as_[4], ad_[4];
        #pragma unroll
        for (int n = 0; n < 4; ++n) {
            as_[n] = avec[h * 128 + n * 16 + l15] * LOG2E;
            ad_[n] = avec[h * 128 + 64 + n * 16 + l15] * LOG2E;
        }
        #pragma unroll
        for (int r = 0; r < 4; ++r) {
            float ps = acc[0][r] * as_[0] + acc[1][r] * as_[1]
                     + acc[2][r] * as_[2] + acc[3][r] * as_[3];
            float pd = acc[0][r] * ad_[0] + acc[1][r] * ad_[1]
                     + acc[2][r] * ad_[2] + acc[3][r] * ad_[3];
            #pragma unroll
            for (int off = 1; off < 16; off <<= 1) {
                ps += __shfl_xor(ps, off);
                pd += __shfl_xor(pd, off);
            }
            if (l15 == 0) {
                const int i = (m0 + wv * 16 + g * 4 + r) & (NN - 1);
                esrc[(size_t)bh * NN + i] = ps;
                edst[(size_t)bh * NN + i] = pd;
            }
        }
    }

    // ---- WhT store via LDS bounce (coalesced) ----
    u16* scr = &Al[0][0];
    #pragma unroll
    for (int n = 0; n < 4; ++n) {
        u16x4v pk;
        #pragma unroll
        for (int r = 0; r < 4; ++r) pk[r] = f2b(acc[n][r]);
        *reinterpret_cast<u16x4v*>(&scr[(n * 16 + l15) * 72 + wv * 16 + g * 4]) = pk;
    }
    __syncthreads();
    const int il0 = m0 & (NN - 1);
    const int f = t >> 2, q = t & 3;
    const u16x8v v0 = *reinterpret_cast<const u16x8v*>(&scr[f * 72 + q * 16]);
    const u16x8v v1 = *reinterpret_cast<const u16x8v*>(&scr[f * 72 + q * 16 + 8]);
    u16* dst = &WhT[((size_t)bh * 64 + f) * NN + il0 + q * 16];
    *reinterpret_cast<u16x8v*>(dst)     = v0;
    *reinterpret_cast<u16x8v*>(dst + 8) = v1;
}

// ---------------------------------------------------------------------------
// attn_pv v6: dual A-fragments — each wave owns 32 rows (mf=0/1), so every
// B-fragment ds_read feeds 2 MFMAs and each V slice is staged 8x not 32x.
// 256 thr / 4 waves / 128 rows, grid 512, XCD-chunked. Counted vmcnt(8)
// barriers, 2-deep ed/bits prefetch, setprio MFMA cluster, dsum via MFMA.
// ---------------------------------------------------------------------------
__global__ __launch_bounds__(256, 2) void attn_pv(const u32* __restrict__ bits,
                                                  const u16* __restrict__ WhT,
                                                  const float* __restrict__ esrc,
                                                  const float* __restrict__ edst,
                                                  float* __restrict__ out) {
    __shared__ u16 Bs[2][64 * 64];             // 16 KB, V tile dbuf
    const int t = threadIdx.x, wv = t >> 6, lane = t & 63;
    const int g = lane >> 4, l15 = lane & 15;
    const int lr = lane >> 3, sch = (lane & 7) ^ lr;

    // XCD chunk: 64 consecutive lids (8 i-chunks x 8 heads of one batch)/XCD
    const int lid = (blockIdx.x & 7) * 64 + (blockIdx.x >> 3);
    const int it = lid & 7, h = (lid >> 3) & 7, b = lid >> 6;
    const int i0 = it * 128;
    const int bh = b * HEADS + h;
    const int row0 = i0 + wv * 32 + l15;       // mf=0 row; mf=1 at +16

    const float es0 = esrc[(size_t)bh * NN + row0];
    const float es1 = esrc[(size_t)bh * NN + row0 + 16];
    const u16*  whb = WhT + (size_t)bh * 64 * NN;
    const float* ed = edst + (size_t)bh * NN + 8 * g;
    const u32*  bitrow0 = bits + (size_t)(b * NN + row0) * 32;
    const u32*  bitrow1 = bitrow0 + 16 * 32;

    auto stageB = [&](int buf, int j0) {
        #pragma unroll
        for (int c = 0; c < 2; ++c) {
            const int fb = wv * 16 + c * 8;
            gload_lds16(whb + (size_t)(fb + lr) * NN + j0 + sch * 8,
                        &Bs[buf][fb * 64]);
        }
    };

    stageB(0, 0);
    // 2-deep register prefetch slots (slot = parity of step s)
    float4 peA[2], peB[2];
    u32    pw0[2], pw1[2];
    #pragma unroll
    for (int s = 0; s < 2; ++s) {
        peA[s] = *(const float4*)(ed + s * 32);
        peB[s] = *(const float4*)(ed + s * 32 + 4);
        pw0[s] = bitrow0[s];
        pw1[s] = bitrow1[s];
    }
    __syncthreads();

    f32x4 acc0[4] = {}, acc1[4] = {};
    f32x4 dsum0 = {}, dsum1 = {};
    bf16x8 ones;
    #pragma unroll
    for (int q = 0; q < 8; ++q) ones[q] = (short)0x3F80;   // bf16(1.0)

    for (int tt = 0; tt < 16; ++tt) {
        const int buf = tt & 1;
        const bool more = (tt < 15);
        if (more) {
            stageB(buf ^ 1, (tt + 1) * 64);
            asm volatile("" ::: "memory");     // pin: prefetches stay after stage
        }
        #pragma unroll
        for (int ks = 0; ks < 2; ++ks) {
            const int s = tt * 2 + ks;
            const float4 e0 = peA[ks], e1 = peB[ks];
            const u32 w0 = pw0[ks], w1 = pw1[ks];
            if (more) {                        // refill slot with step s+2
                peA[ks] = *(const float4*)(ed + (s + 2) * 32);
                peB[ks] = *(const float4*)(ed + (s + 2) * 32 + 4);
                pw0[ks] = bitrow0[s + 2];
                pw1[ks] = bitrow1[s + 2];
            }
            // B fragments early: ds latency hides under p-gen
            const int chb = ((ks * 4 + g) ^ (l15 & 7)) * 8;
            const bf16x8 v0 = *(const bf16x8*)(&Bs[buf][(0 * 16 + l15) * 64 + chb]);
            const bf16x8 v1 = *(const bf16x8*)(&Bs[buf][(1 * 16 + l15) * 64 + chb]);
            const bf16x8 v2 = *(const bf16x8*)(&Bs[buf][(2 * 16 + l15) * 64 + chb]);
            const bf16x8 v3 = *(const bf16x8*)(&Bs[buf][(3 * 16 + l15) * 64 + chb]);

            float ej[8];
            ej[0]=e0.x; ej[1]=e0.y; ej[2]=e0.z; ej[3]=e0.w;
            ej[4]=e1.x; ej[5]=e1.y; ej[6]=e1.z; ej[7]=e1.w;
            const u32 by0 = (w0 >> (8 * g)) & 0xffu;
            const u32 by1 = (w1 >> (8 * g)) & 0xffu;
            float p0[8], p1[8];
            #pragma unroll
            for (int q = 0; q < 8; ++q) {
                float s0 = es0 + ej[q];
                float s1 = es1 + ej[q];
                s0 = fmaxf(s0, ALPHA * s0);
                s1 = fmaxf(s1, ALPHA * s1);
                s0 = ((by0 >> q) & 1u) ? s0 : -1e30f;
                s1 = ((by1 >> q) & 1u) ? s1 : -1e30f;
                p0[q] = fexp2(s0);
                p1[q] = fexp2(s1);
            }
            union { u32 u[4]; bf16x8 v; } af0, af1;
            #pragma unroll
            for (int qp = 0; qp < 4; ++qp) {
                union { __hip_bfloat162 b2; u32 w; } c0, c1;
                c0.b2 = __float22bfloat162_rn(make_float2(p0[2*qp], p0[2*qp+1]));
                c1.b2 = __float22bfloat162_rn(make_float2(p1[2*qp], p1[2*qp+1]));
                af0.u[qp] = c0.w;
                af1.u[qp] = c1.w;
            }
            __builtin_amdgcn_s_setprio(1);
            acc0[0] = __builtin_amdgcn_mfma_f32_16x16x32_bf16(af0.v, v0, acc0[0], 0, 0, 0);
            acc1[0] = __builtin_amdgcn_mfma_f32_16x16x32_bf16(af1.v, v0, acc1[0], 0, 0, 0);
            acc0[1] = __builtin_amdgcn_mfma_f32_16x16x32_bf16(af0.v, v1, acc0[1], 0, 0, 0);
            acc1[1] = __builtin_amdgcn_mfma_f32_16x16x32_bf16(af1.v, v1, acc1[1], 0, 0, 0);
            acc0[2] = __builtin_amdgcn_mfma_f32_16x16x32_bf16(af0.v, v2, acc0[2], 0, 0, 0);
            acc1[2] = __builtin_amdgcn_mfma_f32_16x16x32_bf16(af1.v, v2, acc1[2], 0, 0, 0);
            acc0[3] = __builtin_amdgcn_mfma_f32_16x16x32_bf16(af0.v, v3, acc0[3], 0, 0, 0);
            acc1[3] = __builtin_amdgcn_mfma_f32_16x16x32_bf16(af1.v, v3, acc1[3], 0, 0, 0);
            dsum0   = __builtin_amdgcn_mfma_f32_16x16x32_bf16(af0.v, ones, dsum0, 0, 0, 0);
            dsum1   = __builtin_amdgcn_mfma_f32_16x16x32_bf16(af1.v, ones, dsum1, 0, 0, 0);
            __builtin_amdgcn_s_setprio(0);
        }
        if (more) {
            // per-wave VMEM this tile: 2 stage + 8 prefetch -> vmcnt(8)
            // guarantees the stage landed, leaves prefetches in flight (T4).
            asm volatile("s_waitcnt vmcnt(8)" ::: "memory");
            __builtin_amdgcn_s_barrier();
        }
    }

    float inv0[4], inv1[4];
    #pragma unroll
    for (int r = 0; r < 4; ++r) { inv0[r] = 1.0f / dsum0[r]; inv1[r] = 1.0f / dsum1[r]; }
    #pragma unroll
    for (int n = 0; n < 4; ++n)
        #pragma unroll
        for (int r = 0; r < 4; ++r) {
            const int io0 = i0 + wv * 32 + g * 4 + r;
            out[(size_t)(b * NN + io0) * NH + h * 64 + n * 16 + l15] =
                acc0[n][r] * inv0[r];
            out[(size_t)(b * NN + io0 + 16) * NH + h * 64 + n * 16 + l15] =
                acc1[n][r] * inv1[r];
        }
}

// ---------------------------------------------------------------------------
extern "C" void kernel_launch(void* const* d_in, const int* in_sizes, int n_in,
                              void* d_out, int out_size, void* d_ws, size_t ws_size,
                              hipStream_t stream) {
    const float* h   = (const float*)d_in[0];
    const int*   adj = (const int*)  d_in[1];
    const float* W   = (const float*)d_in[2];
    const float* a   = (const float*)d_in[3];
    float* out = (float*)d_out;

    char* p = (char*)d_ws;
    u16*   hb   = (u16*)p;   p += (size_t)BS * NN * FIN * 2;        // 4 MB
    u16*   WbT  = (u16*)p;   p += (size_t)NH * FIN * 2;             // 256 KB
    u16*   WhT  = (u16*)p;   p += (size_t)BS * HEADS * FO * NN * 2; // 8 MB
    float* esrc = (float*)p; p += (size_t)BS * HEADS * NN * 4;      // 256 KB
    float* edst = (float*)p; p += (size_t)BS * HEADS * NN * 4;      // 256 KB
    u32*   bits = (u32*)p;                                          // 1 MB

    prep_misc<<<9248, 256, 0, stream>>>(h, adj, W, hb, WbT, bits);
    gemm_whT <<<1024, 256, 0, stream>>>(hb, WbT, a, WhT, esrc, edst);
    attn_pv  <<<512, 256, 0, stream>>>(bits, WhT, esrc, edst, out);
}